// Round 5
// baseline (350.218 us; speedup 1.0000x reference)
//
#include <hip/hip_runtime.h>
#include <math.h>
#include <float.h>
#include <limits.h>
#include <stdint.h>

namespace {

constexpr int B  = 2;
constexpr int CK = 64;
constexpr int N  = 12960;   // T*H*W = 8*30*54
constexpr int M  = 1620;    // H*W = 30*54
constexpr int CV = 384;
constexpr int K  = 20;      // topk (setup fixed)
constexpr int RS = 13312;   // key16 row stride = 52*256 (N padded, pad key = 0)
constexpr int JK = 52;      // keys per thread in topk (52*256 = RS)
constexpr int CCAP = 128;   // candidate cap (boundary-bin ties; expected ~1-2)

// monotone float->uint key (order-preserving)
__device__ __forceinline__ uint32_t f2k(float x) {
  uint32_t u = __float_as_uint(x);
  return u ^ ((u & 0x80000000u) ? 0xFFFFFFFFu : 0x80000000u);
}

// flat per-thread key slot -> n  (4 keys per uint2 load, load j>>2 at t+(j>>2)*256)
__device__ __forceinline__ int nOf(int t, int jj) {
  return 4 * (t + ((jj >> 2) << 8)) + (jj & 3);
}

// generic [C][N] -> [N][C] transpose (C multiple of 64)
__global__ __launch_bounds__(256) void transpose_in_kernel(const float* __restrict__ src,
                                                           float* __restrict__ dst, int C) {
  __shared__ float tile[64][65];
  int b = blockIdx.z;
  int n0 = blockIdx.x * 64;
  int c0 = blockIdx.y * 64;
  int tx = threadIdx.x & 63, ty = threadIdx.x >> 6;
  for (int r = ty; r < 64; r += 4) {
    int c = c0 + r, n = n0 + tx;
    tile[r][tx] = (n < N) ? src[((size_t)b * C + c) * N + n] : 0.f;
  }
  __syncthreads();
  for (int r = ty; r < 64; r += 4) {
    int n = n0 + r, c = c0 + tx;
    if (n < N) dst[((size_t)b * N + n) * C + c] = tile[tx][r];
  }
}

// out[b][c][m] = outT[b][m][c]
__global__ __launch_bounds__(256) void transpose_out_kernel(const float* __restrict__ outT,
                                                            float* __restrict__ out) {
  __shared__ float tile[64][65];
  int b = blockIdx.z;
  int m0 = blockIdx.x * 64;
  int c0 = blockIdx.y * 64;
  int tx = threadIdx.x & 63, ty = threadIdx.x >> 6;
  for (int r = ty; r < 64; r += 4) {
    int m = m0 + r;
    if (m < M) tile[r][tx] = outT[((size_t)b * M + m) * CV + c0 + tx];
  }
  __syncthreads();
  for (int r = ty; r < 64; r += 4) {
    int c = c0 + r, m = m0 + tx;
    if (m < M) out[((size_t)b * CV + c) * M + m] = tile[tx][r];
  }
}

// a_sq[b,n] = sum_c mk[b,c,n]^2
__global__ __launch_bounds__(256) void asq_kernel(const float* __restrict__ mk,
                                                  float* __restrict__ asq) {
  int i = blockIdx.x * 256 + threadIdx.x;
  if (i >= B * N) return;
  int b = i / N, n = i - b * N;
  const float* p = mk + (size_t)b * CK * N + n;
  float s = 0.f;
#pragma unroll
  for (int c = 0; c < CK; ++c) {
    float v = p[(size_t)c * N];
    s += v * v;
  }
  asq[i] = s;
}

// aff16[b][mi][n] = top 16 bits of monotone key of (2*dot - asq)/8.
// Same c-ascending per-element FMA chain as the fp32 version -> same ordering.
// Grid: (mTiles, RS/256, B) with x = m-tile so consecutive blocks reuse qk/mk in L2/L3.
__global__ __launch_bounds__(256) void aff16_kernel(const float* __restrict__ mk,
                                                    const float* __restrict__ qk,
                                                    const float* __restrict__ asq,
                                                    unsigned short* __restrict__ aff16,
                                                    int m0, int mcAct, int mcAlloc) {
  int b = blockIdx.z;
  int mbase = blockIdx.x * 64;
  __shared__ float qs[CK][68];  // row stride 272 B (16B-aligned, non-pow2 banks)
  int t = threadIdx.x;
  for (int l = t; l < CK * 64; l += 256) {
    int c = l >> 6, ml = l & 63;
    int mg = m0 + mbase + ml;
    qs[c][ml] = (mbase + ml < mcAct) ? qk[((size_t)b * CK + c) * M + mg] : 0.f;
  }
  __syncthreads();

  int n0 = blockIdx.y * 256 + (t & 63) * 4;
  int mg = (t >> 6) * 16;  // wave-uniform -> qs reads broadcast

  if (n0 >= N) {  // pad region [N, RS): key 0 (below all real keys)
    ushort4 z; z.x = 0; z.y = 0; z.z = 0; z.w = 0;
#pragma unroll
    for (int j = 0; j < 16; ++j) {
      int mi = mbase + mg + j;
      if (mi < mcAct)
        *reinterpret_cast<ushort4*>(aff16 + ((size_t)b * mcAlloc + mi) * RS + n0) = z;
    }
    return;
  }

  const float* mkb = mk + (size_t)b * CK * N + n0;
  float4 acc[16];
#pragma unroll
  for (int j = 0; j < 16; ++j) acc[j] = make_float4(0.f, 0.f, 0.f, 0.f);

#pragma unroll 4
  for (int c = 0; c < CK; ++c) {
    const float4 kv = *reinterpret_cast<const float4*>(mkb + (size_t)c * N);
    const float4 q0 = *reinterpret_cast<const float4*>(&qs[c][mg]);
    const float4 q1 = *reinterpret_cast<const float4*>(&qs[c][mg + 4]);
    const float4 q2 = *reinterpret_cast<const float4*>(&qs[c][mg + 8]);
    const float4 q3 = *reinterpret_cast<const float4*>(&qs[c][mg + 12]);
    const float qv[16] = {q0.x, q0.y, q0.z, q0.w, q1.x, q1.y, q1.z, q1.w,
                          q2.x, q2.y, q2.z, q2.w, q3.x, q3.y, q3.z, q3.w};
#pragma unroll
    for (int j = 0; j < 16; ++j) {
      acc[j].x += kv.x * qv[j];
      acc[j].y += kv.y * qv[j];
      acc[j].z += kv.z * qv[j];
      acc[j].w += kv.w * qv[j];
    }
  }
  const float4 sq = *reinterpret_cast<const float4*>(asq + (size_t)b * N + n0);
#pragma unroll
  for (int j = 0; j < 16; ++j) {
    int mi = mbase + mg + j;
    if (mi < mcAct) {
      ushort4 kk;
      kk.x = (unsigned short)(f2k((2.f * acc[j].x - sq.x) * 0.125f) >> 16);
      kk.y = (unsigned short)(f2k((2.f * acc[j].y - sq.y) * 0.125f) >> 16);
      kk.z = (unsigned short)(f2k((2.f * acc[j].z - sq.z) * 0.125f) >> 16);
      kk.w = (unsigned short)(f2k((2.f * acc[j].w - sq.w) * 0.125f) >> 16);
      *reinterpret_cast<ushort4*>(aff16 + ((size_t)b * mcAlloc + mi) * RS + n0) = kk;
    }
  }
}

// 2-pass radix select on key16 -> candidates (key >= thr16) -> exact fp32
// recompute from mkT (same serial fma chain) -> exact top-20 (val desc, idx asc)
// -> softmax on exact values -> fused gather to outT[b][m][c].
__global__ __launch_bounds__(256) void topk16_gather_kernel(
    const unsigned short* __restrict__ aff16, const float* __restrict__ mkT,
    const float* __restrict__ qk, const float* __restrict__ asq,
    const float* __restrict__ mvT, int m0, int mcAlloc, float* __restrict__ outT) {
  const int mi = blockIdx.x, b = blockIdx.y;
  const int m = m0 + mi;
  const int t = threadIdx.x;
  const uint2* row8 = reinterpret_cast<const uint2*>(aff16 + ((size_t)b * mcAlloc + mi) * RS);

  uint32_t k[JK];
#pragma unroll
  for (int j = 0; j < 13; ++j) {
    uint2 v = row8[t + (j << 8)];
    k[4 * j + 0] = v.x & 0xFFFFu;
    k[4 * j + 1] = v.x >> 16;
    k[4 * j + 2] = v.y & 0xFFFFu;
    k[4 * j + 3] = v.y >> 16;
  }

  constexpr int HP = 268;
  __shared__ int hist[4][4][HP];
  __shared__ int s_digit, s_before;
  __shared__ int cand[CCAP];
  __shared__ float cval[CCAP];
  __shared__ int ccnt;
  __shared__ float qm[CK];
  __shared__ float wv[K];
  __shared__ int wnn[K];
  __shared__ float sw[K];

  if (t < CK) qm[t] = qk[((size_t)b * CK + t) * M + m];

  int before = 0;
  uint32_t pref = 0;
  const int w = t >> 6;
  const int rp = (t >> 4) & 3;
  int* myhist = &hist[w][rp][0];

  for (int p = 0; p < 2; ++p) {
    const int s = 8 - 8 * p;
    for (int l = t; l < 16 * HP; l += 256) ((int*)hist)[l] = 0;
    __syncthreads();
#pragma unroll
    for (int j = 0; j < JK; ++j) {
      uint32_t key = k[j];
      bool act = (p == 0) || ((key >> 8) == pref);
      if (act) atomicAdd(&myhist[(key >> s) & 255], 1);
    }
    __syncthreads();
    if (t < 64) {
      int d = 4 * t;
      int4 g = make_int4(0, 0, 0, 0);
#pragma unroll
      for (int ww = 0; ww < 4; ++ww)
#pragma unroll
        for (int rr = 0; rr < 4; ++rr) {
          int4 h = *reinterpret_cast<int4*>(&hist[ww][rr][d]);
          g.x += h.x; g.y += h.y; g.z += h.z; g.w += h.w;
        }
      int sl = g.x + g.y + g.z + g.w;
      int sfx = sl;
#pragma unroll
      for (int off = 1; off < 64; off <<= 1) {
        int o = __shfl_down(sfx, off);
        sfx += (t + off < 64) ? o : 0;
      }
      int above = sfx - sl;
      int rem = K - before;
      if (above < rem && rem <= sfx) {  // boundary digit in my 4-digit group
        int cum = above, ds;
        if (cum + g.w >= rem) ds = 3;
        else { cum += g.w;
          if (cum + g.z >= rem) ds = 2;
          else { cum += g.z;
            if (cum + g.y >= rem) ds = 1;
            else { cum += g.y; ds = 0; } } }
        s_digit = 4 * t + ds;
        s_before = before + cum;
      }
    }
    __syncthreads();
    pref = (pref << 8) | (uint32_t)s_digit;
    before = s_before;
  }

  const uint32_t thr = pref;  // key16 of the rank-20 element
  if (t == 0) ccnt = 0;
  __syncthreads();
#pragma unroll
  for (int j = 0; j < JK; ++j) {
    if (k[j] >= thr) {
      int q = atomicAdd(&ccnt, 1);
      if (q < CCAP) cand[q] = nOf(t, j);  // pad keys are 0 < thr: never collected
    }
  }
  __syncthreads();
  const int nc = min(ccnt, CCAP);  // >= 20 by construction

  // exact fp32 recompute for candidates (serial c-ascending fma chain == aff chain)
  for (int q = t; q < nc; q += 256) {
    int n = cand[q];
    const float* kr = mkT + ((size_t)b * N + n) * CK;
    float s = 0.f;
#pragma unroll
    for (int c = 0; c < CK; ++c) s = fmaf(kr[c], qm[c], s);
    cval[q] = (2.f * s - asq[(size_t)b * N + n]) * 0.125f;
  }
  __syncthreads();

  // exact top-20 among candidates (value desc, index asc), wave 0, 2 slots/lane
  if (t < 64) {
    float v0 = (t < nc) ? cval[t] : -FLT_MAX;
    int n0_ = (t < nc) ? cand[t] : INT_MAX;
    float v1 = (t + 64 < nc) ? cval[t + 64] : -FLT_MAX;
    int n1_ = (t + 64 < nc) ? cand[t + 64] : INT_MAX;
    for (int r = 0; r < K; ++r) {
      float bv; int bn;
      if (v0 > v1 || (v0 == v1 && n0_ < n1_)) { bv = v0; bn = n0_; }
      else { bv = v1; bn = n1_; }
#pragma unroll
      for (int off = 1; off < 64; off <<= 1) {
        float ov = __shfl_xor(bv, off);
        int on = __shfl_xor(bn, off);
        if (ov > bv || (ov == bv && on < bn)) { bv = ov; bn = on; }
      }
      if (t == 0) { wv[r] = bv; wnn[r] = bn; }
      if (bn == n0_) v0 = -FLT_MAX;
      if (bn == n1_) v1 = -FLT_MAX;
    }
  }
  __syncthreads();

  // softmax over the K winners (wave 0)
  if (t < 64) {
    float v = (t < K) ? wv[t] : -FLT_MAX;
    float mx = v;
#pragma unroll
    for (int off = 1; off < 64; off <<= 1) mx = fmaxf(mx, __shfl_xor(mx, off));
    float e = (t < K) ? expf(v - mx) : 0.f;
    float ss = e;
#pragma unroll
    for (int off = 1; off < 64; off <<= 1) ss += __shfl_xor(ss, off);
    if (t < K) sw[t] = e / ss;
  }
  __syncthreads();

  // fused gather: outT[b][m][c] = sum_j sw[j] * mvT[b][wnn[j]][c]  (float4 rows)
  if (t < CV / 4) {
    const float4* tb4 = reinterpret_cast<const float4*>(mvT + (size_t)b * N * CV);
    float4 s = make_float4(0.f, 0.f, 0.f, 0.f);
#pragma unroll
    for (int j = 0; j < K; ++j) {
      float wj = sw[j];
      float4 v = tb4[(size_t)wnn[j] * (CV / 4) + t];
      s.x += wj * v.x; s.y += wj * v.y; s.z += wj * v.z; s.w += wj * v.w;
    }
    reinterpret_cast<float4*>(outT + ((size_t)b * M + m) * CV)[t] = s;
  }
}

}  // namespace

extern "C" void kernel_launch(void* const* d_in, const int* in_sizes, int n_in,
                              void* d_out, int out_size, void* d_ws, size_t ws_size,
                              hipStream_t stream) {
  const float* mk = (const float*)d_in[0];
  const float* qk = (const float*)d_in[1];
  const float* mv = (const float*)d_in[2];
  float* out = (float*)d_out;

  char* w = (char*)d_ws;
  float* asq = (float*)w;
  size_t o = (size_t)B * N * sizeof(float);            // 103,680 B
  float* mvT = (float*)(w + o);
  o += (size_t)B * N * CV * sizeof(float);             // +39,813,120 B
  float* mkT = (float*)(w + o);
  o += (size_t)B * N * CK * sizeof(float);             // +6,635,520 B
  float* outT = (float*)(w + o);
  o += (size_t)B * M * CV * sizeof(float);             // +4,976,640 B
  unsigned short* aff16 = (unsigned short*)(w + o);

  // chunk M so the key16 buffer [B][mcAlloc][RS] (ushort) fits in workspace
  size_t avail = (ws_size > o) ? (ws_size - o) : 0;
  long cols = (long)(avail / ((size_t)B * RS * sizeof(unsigned short)));
  int mcAlloc = (int)(cols & ~63L);
  if (mcAlloc < 64) mcAlloc = 64;      // best-effort floor
  if (mcAlloc > 1664) mcAlloc = 1664;  // single-chunk cap (covers M=1620)

  transpose_in_kernel<<<dim3((N + 63) / 64, CV / 64, B), 256, 0, stream>>>(mv, mvT, CV);
  transpose_in_kernel<<<dim3((N + 63) / 64, CK / 64, B), 256, 0, stream>>>(mk, mkT, CK);
  asq_kernel<<<(B * N + 255) / 256, 256, 0, stream>>>(mk, asq);

  for (int m0 = 0; m0 < M; m0 += mcAlloc) {
    int mcAct = (M - m0 < mcAlloc) ? (M - m0) : mcAlloc;
    dim3 ga((mcAct + 63) / 64, RS / 256, B);
    aff16_kernel<<<ga, 256, 0, stream>>>(mk, qk, asq, aff16, m0, mcAct, mcAlloc);
    topk16_gather_kernel<<<dim3(mcAct, B), 256, 0, stream>>>(aff16, mkT, qk, asq, mvT,
                                                             m0, mcAlloc, outT);
  }

  transpose_out_kernel<<<dim3((M + 63) / 64, CV / 64, B), 256, 0, stream>>>(outT, out);
}